// Round 1
// baseline (911.021 us; speedup 1.0000x reference)
//
#include <hip/hip_runtime.h>

#define NELEM 500000
#define NGP 4
#define NDOF 500000
#define HID 64

// tanh(x) = 1 - 2/(exp(2x)+1); clamp so exp stays finite. v_exp + v_rcp fast path.
__device__ __forceinline__ float fast_tanh(float x) {
    float cx = fminf(fmaxf(x, -15.0f), 15.0f);
    float e = __expf(2.0f * cx);
    float r = __builtin_amdgcn_rcpf(e + 1.0f);
    return fmaf(-2.0f, r, 1.0f);
}

// block=256: __launch_bounds__(256,2) -> VGPR cap 256 (we need ~200: 128 for two
// h1 arrays + accumulators); 2 blocks/CU = 8 waves/CU.
__global__ __launch_bounds__(256, 2) void fem_force_kernel(
    const float* __restrict__ u, const float* __restrict__ B,
    const float* __restrict__ Jacc, const float* __restrict__ gp_w,
    const int* __restrict__ conn, const float* __restrict__ weight1,
    const float* __restrict__ scales_inp, const float* __restrict__ limits_inp,
    const float* __restrict__ scales_grad, const float* __restrict__ limits_grad,
    const float* __restrict__ W1, const float* __restrict__ b1,
    const float* __restrict__ W2, const float* __restrict__ b2,
    const float* __restrict__ W3, const float* __restrict__ b3,
    float* __restrict__ F)
{
    __shared__ float sW1[2 * HID];
    __shared__ float sb1[HID];
    __shared__ float sW2[HID * HID];
    __shared__ float sb2[HID];
    __shared__ float sW3[HID * 2];

    {
        const int t = threadIdx.x;
        for (int i = t; i < HID * HID; i += 256) sW2[i] = W2[i];
        if (t < 2 * HID) { sW1[t] = W1[t]; sW3[t] = W3[t]; }
        if (t < HID)     { sb1[t] = b1[t]; sb2[t] = b2[t]; }
    }
    __syncthreads();

    const int e = blockIdx.x * 256 + threadIdx.x;
    if (e >= NELEM) return;

    const float SQ23 = 0.816496580927726f;
    const float si0 = scales_inp[0], si1 = scales_inp[1];
    const float li0 = limits_inp[0], li1 = limits_inp[1];
    const float isg0 = 1.0f / scales_grad[0], isg1 = 1.0f / scales_grad[1];
    const float lg0 = limits_grad[0], lg1 = limits_grad[1];
    const float b30 = b3[0], b31 = b3[1];

    // elemental dof indices (interleaved 2n, 2n+1) and weighted displacements
    const int4 c4 = ((const int4*)conn)[e];
    int ed[8];
    ed[0] = 2 * c4.x; ed[1] = ed[0] + 1;
    ed[2] = 2 * c4.y; ed[3] = ed[2] + 1;
    ed[4] = 2 * c4.z; ed[5] = ed[4] + 1;
    ed[6] = 2 * c4.w; ed[7] = ed[6] + 1;
    float ue[8];
#pragma unroll
    for (int j = 0; j < 8; j++) ue[j] = weight1[ed[j]] * u[ed[j]];

    float EP[8] = {0.f, 0.f, 0.f, 0.f, 0.f, 0.f, 0.f, 0.f};

    // process gauss points in pairs so each W2 LDS read feeds 8 FMAs
#pragma unroll 1
    for (int gp = 0; gp < 2; gp++) {
        float nsA0, nsA1, nsB0, nsB1;
        float dA00, dA11, dA01, rdA;
        float dB00, dB11, dB01, rdB;

#pragma unroll
        for (int h = 0; h < 2; h++) {
            const int gg = 2 * gp + h;
            const float4* Bp = (const float4*)(B + ((size_t)e * NGP + gg) * 24);
            float Bg[24];
#pragma unroll
            for (int t2 = 0; t2 < 6; t2++) {
                float4 v = Bp[t2];
                Bg[4 * t2 + 0] = v.x; Bg[4 * t2 + 1] = v.y;
                Bg[4 * t2 + 2] = v.z; Bg[4 * t2 + 3] = v.w;
            }
            float s0 = 0.f, s1 = 0.f, s2 = 0.f;
#pragma unroll
            for (int j = 0; j < 8; j++) {
                s0 = fmaf(Bg[j],      ue[j], s0);
                s1 = fmaf(Bg[8 + j],  ue[j], s1);
                s2 = fmaf(Bg[16 + j], ue[j], s2);
            }
            const float ev  = s0 + s1;
            const float ev3 = ev * (1.0f / 3.0f);
            const float d00 = s0 - ev3, d11 = s1 - ev3, d22 = -ev3, d01 = 0.5f * s2;
            const float det = sqrtf(d00 * d00 + d11 * d11 + d22 * d22 + 2.0f * d01 * d01);
            const float rd  = 1.0f / det;
            const float es  = det * SQ23;
            const float n0  = fmaf(ev, si0, li0);
            const float n1  = fmaf(es, si1, li1);
            if (h == 0) { dA00 = d00; dA11 = d11; dA01 = d01; rdA = rd; nsA0 = n0; nsA1 = n1; }
            else        { dB00 = d00; dB11 = d11; dB01 = d01; rdB = rd; nsB0 = n0; nsB1 = n1; }
        }

        // layer 1: 2 -> 64, tanh (both gauss points share the W1/b1 reads)
        float h1a[HID], h1b[HID];
#pragma unroll
        for (int jg = 0; jg < 16; jg++) {
            float4 wa = ((const float4*)sW1)[jg];
            float4 wb = ((const float4*)(sW1 + HID))[jg];
            float4 bb = ((const float4*)sb1)[jg];
            h1a[4 * jg + 0] = fast_tanh(fmaf(nsA0, wa.x, fmaf(nsA1, wb.x, bb.x)));
            h1a[4 * jg + 1] = fast_tanh(fmaf(nsA0, wa.y, fmaf(nsA1, wb.y, bb.y)));
            h1a[4 * jg + 2] = fast_tanh(fmaf(nsA0, wa.z, fmaf(nsA1, wb.z, bb.z)));
            h1a[4 * jg + 3] = fast_tanh(fmaf(nsA0, wa.w, fmaf(nsA1, wb.w, bb.w)));
            h1b[4 * jg + 0] = fast_tanh(fmaf(nsB0, wa.x, fmaf(nsB1, wb.x, bb.x)));
            h1b[4 * jg + 1] = fast_tanh(fmaf(nsB0, wa.y, fmaf(nsB1, wb.y, bb.y)));
            h1b[4 * jg + 2] = fast_tanh(fmaf(nsB0, wa.z, fmaf(nsB1, wb.z, bb.z)));
            h1b[4 * jg + 3] = fast_tanh(fmaf(nsB0, wa.w, fmaf(nsB1, wb.w, bb.w)));
        }

        // layer 2 (64x64, tanh) with layer 3 (64->2) fused per j-group
        float gA0 = b30, gA1 = b31, gB0 = b30, gB1 = b31;
#pragma unroll 1
        for (int jg = 0; jg < 16; jg++) {
            float4 accA = ((const float4*)sb2)[jg];
            float4 accB = accA;
#pragma unroll
            for (int k = 0; k < HID; k++) {
                float4 w = ((const float4*)sW2)[k * 16 + jg];
                accA.x = fmaf(h1a[k], w.x, accA.x);
                accA.y = fmaf(h1a[k], w.y, accA.y);
                accA.z = fmaf(h1a[k], w.z, accA.z);
                accA.w = fmaf(h1a[k], w.w, accA.w);
                accB.x = fmaf(h1b[k], w.x, accB.x);
                accB.y = fmaf(h1b[k], w.y, accB.y);
                accB.z = fmaf(h1b[k], w.z, accB.z);
                accB.w = fmaf(h1b[k], w.w, accB.w);
            }
            const float tA0 = fast_tanh(accA.x), tA1 = fast_tanh(accA.y);
            const float tA2 = fast_tanh(accA.z), tA3 = fast_tanh(accA.w);
            const float tB0 = fast_tanh(accB.x), tB1 = fast_tanh(accB.y);
            const float tB2 = fast_tanh(accB.z), tB3 = fast_tanh(accB.w);
            float4 w3a = ((const float4*)sW3)[2 * jg];
            float4 w3b = ((const float4*)sW3)[2 * jg + 1];
            gA0 = fmaf(tA0, w3a.x, fmaf(tA1, w3a.z, fmaf(tA2, w3b.x, fmaf(tA3, w3b.z, gA0))));
            gA1 = fmaf(tA0, w3a.y, fmaf(tA1, w3a.w, fmaf(tA2, w3b.y, fmaf(tA3, w3b.w, gA1))));
            gB0 = fmaf(tB0, w3a.x, fmaf(tB1, w3a.z, fmaf(tB2, w3b.x, fmaf(tB3, w3b.z, gB0))));
            gB1 = fmaf(tB0, w3a.y, fmaf(tB1, w3a.w, fmaf(tB2, w3b.y, fmaf(tB3, w3b.w, gB1))));
        }

        // epilogue: stress -> E_P accumulation (B re-read; L2-resident)
#pragma unroll
        for (int h = 0; h < 2; h++) {
            const int gg = 2 * gp + h;
            const float g0 = h ? gB0 : gA0;
            const float g1 = h ? gB1 : gA1;
            const float d00 = h ? dB00 : dA00;
            const float d11 = h ? dB11 : dA11;
            const float d01 = h ? dB01 : dA01;
            const float rd  = h ? rdB  : rdA;
            const float p = (g0 - lg0) * isg0;
            const float q = (g1 - lg1) * isg1;
            const float crd = SQ23 * q * rd;
            const float wgt = Jacc[e * NGP + gg] * gp_w[gg];  // WIDTH = 1
            const float f0 = fmaf(crd, d00, p) * wgt;
            const float f1 = fmaf(crd, d11, p) * wgt;
            const float f2 = (crd * d01) * wgt;
            const float4* Bp = (const float4*)(B + ((size_t)e * NGP + gg) * 24);
            float4 v0 = Bp[0], v1 = Bp[1], v2 = Bp[2], v3 = Bp[3], v4 = Bp[4], v5 = Bp[5];
            EP[0] = fmaf(v0.x, f0, fmaf(v2.x, f1, fmaf(v4.x, f2, EP[0])));
            EP[1] = fmaf(v0.y, f0, fmaf(v2.y, f1, fmaf(v4.y, f2, EP[1])));
            EP[2] = fmaf(v0.z, f0, fmaf(v2.z, f1, fmaf(v4.z, f2, EP[2])));
            EP[3] = fmaf(v0.w, f0, fmaf(v2.w, f1, fmaf(v4.w, f2, EP[3])));
            EP[4] = fmaf(v1.x, f0, fmaf(v3.x, f1, fmaf(v5.x, f2, EP[4])));
            EP[5] = fmaf(v1.y, f0, fmaf(v3.y, f1, fmaf(v5.y, f2, EP[5])));
            EP[6] = fmaf(v1.z, f0, fmaf(v3.z, f1, fmaf(v5.z, f2, EP[6])));
            EP[7] = fmaf(v1.w, f0, fmaf(v3.w, f1, fmaf(v5.w, f2, EP[7])));
        }
    }

    // scatter-add into global force vector
#pragma unroll
    for (int j = 0; j < 8; j++) atomicAdd(&F[ed[j]], EP[j]);
}

extern "C" void kernel_launch(void* const* d_in, const int* in_sizes, int n_in,
                              void* d_out, int out_size, void* d_ws, size_t ws_size,
                              hipStream_t stream) {
    const float* u           = (const float*)d_in[0];
    const float* B           = (const float*)d_in[1];
    const float* Jacc        = (const float*)d_in[2];
    const float* gp_w        = (const float*)d_in[3];
    const int*   conn        = (const int*)  d_in[4];
    const float* weight1     = (const float*)d_in[5];
    const float* scales_inp  = (const float*)d_in[6];
    const float* limits_inp  = (const float*)d_in[7];
    const float* scales_grad = (const float*)d_in[8];
    const float* limits_grad = (const float*)d_in[9];
    const float* W1          = (const float*)d_in[10];
    const float* b1          = (const float*)d_in[11];
    const float* W2          = (const float*)d_in[12];
    const float* b2          = (const float*)d_in[13];
    const float* W3          = (const float*)d_in[14];
    const float* b3          = (const float*)d_in[15];
    float* F = (float*)d_out;

    hipMemsetAsync(d_out, 0, sizeof(float) * NDOF, stream);

    const int grid = (NELEM + 255) / 256;
    fem_force_kernel<<<grid, 256, 0, stream>>>(
        u, B, Jacc, gp_w, conn, weight1, scales_inp, limits_inp,
        scales_grad, limits_grad, W1, b1, W2, b2, W3, b3, F);
}

// Round 3
// 528.505 us; speedup vs baseline: 1.7238x; 1.7238x over previous
//
#include <hip/hip_runtime.h>

#define NELEM 500000
#define NGP 4
#define NDOF 500000
#define HID 64

typedef _Float16 half2v __attribute__((ext_vector_type(2)));

// cvt_pkrtz returns __fp16x2; bit-cast to the _Float16x2 type fdot2 wants.
__device__ __forceinline__ half2v pk(float a, float b) {
    return __builtin_bit_cast(half2v, __builtin_amdgcn_cvt_pkrtz(a, b));
}

// tanh(x) = 1 - 2/(exp(2x)+1); med3 clamp keeps exp finite.
__device__ __forceinline__ float fast_tanh(float x) {
    float cx = __builtin_amdgcn_fmed3f(x, -15.0f, 15.0f);
    float e = __expf(2.0f * cx);
    float r = __builtin_amdgcn_rcpf(e + 1.0f);
    return fmaf(-2.0f, r, 1.0f);
}

__device__ __forceinline__ float fdot2(half2v a, half2v b, float c) {
    return __builtin_amdgcn_fdot2(a, b, c, false);
}

// Thread-per-element, all 4 gauss points held in registers (h1 packed f16:
// 4*32 half2 = 128 VGPRs) so each W2 ds_read_b128 (4 packed pairs) feeds
// 16 v_dot2_f32_f16 = 32 MACs. launch_bounds(256,2) -> VGPR cap 256.
__global__ __launch_bounds__(256, 2) void fem_force_kernel(
    const float* __restrict__ u, const float* __restrict__ B,
    const float* __restrict__ Jacc, const float* __restrict__ gp_w,
    const int* __restrict__ conn, const float* __restrict__ weight1,
    const float* __restrict__ scales_inp, const float* __restrict__ limits_inp,
    const float* __restrict__ scales_grad, const float* __restrict__ limits_grad,
    const float* __restrict__ W1, const float* __restrict__ b1,
    const float* __restrict__ W2, const float* __restrict__ b2,
    const float* __restrict__ W3, const float* __restrict__ b3,
    float* __restrict__ F)
{
    // W2 packed: idx = jg*128 + kp*4 + jj  (j = 4*jg+jj, k-pair = (2kp, 2kp+1))
    // -> uint4 view index jg*32+kp gives the 4 jj's of one k-pair in 16 B.
    __shared__ __align__(16) half2v sW2p[16 * 128];  // 8 KB
    __shared__ __align__(16) half2v sW1p[HID];
    __shared__ __align__(16) float  sb1[HID];
    __shared__ __align__(16) float  sb2[HID];
    __shared__ __align__(16) float  sW3[HID * 2];

    {
        const int t = threadIdx.x;
        for (int idx = t; idx < 2048; idx += 256) {
            const int jg = idx >> 7, rem = idx & 127, kp = rem >> 2, jj = rem & 3;
            const int j = 4 * jg + jj;
            sW2p[idx] = pk(W2[(2 * kp) * HID + j], W2[(2 * kp + 1) * HID + j]);
        }
        if (t < HID) {
            sW1p[t] = pk(W1[t], W1[HID + t]);
            sb1[t] = b1[t];
            sb2[t] = b2[t];
        }
        if (t < 2 * HID) sW3[t] = W3[t];
    }
    __syncthreads();

    const int e = blockIdx.x * 256 + threadIdx.x;
    if (e >= NELEM) return;

    const float SQ23 = 0.816496580927726f;
    const float si0 = scales_inp[0], si1 = scales_inp[1];
    const float li0 = limits_inp[0], li1 = limits_inp[1];
    const float isg0 = 1.0f / scales_grad[0], isg1 = 1.0f / scales_grad[1];
    const float lg0 = limits_grad[0], lg1 = limits_grad[1];
    const float b30 = b3[0], b31 = b3[1];

    const int4 c4 = ((const int4*)conn)[e];
    int ed[8];
    ed[0] = 2 * c4.x; ed[1] = ed[0] + 1;
    ed[2] = 2 * c4.y; ed[3] = ed[2] + 1;
    ed[4] = 2 * c4.z; ed[5] = ed[4] + 1;
    ed[6] = 2 * c4.w; ed[7] = ed[6] + 1;
    float ue[8];
#pragma unroll
    for (int j = 0; j < 8; j++) ue[j] = weight1[ed[j]] * u[ed[j]];

    // ---- phase 1: strain invariants for all 4 gauss points ----
    float d00s[4], d11s[4], d01s[4], rds[4], wgt[4];
    half2v xps[4];
    const float4 jv = ((const float4*)Jacc)[e];
    wgt[0] = jv.x * gp_w[0]; wgt[1] = jv.y * gp_w[1];
    wgt[2] = jv.z * gp_w[2]; wgt[3] = jv.w * gp_w[3];

#pragma unroll
    for (int g = 0; g < NGP; g++) {
        const float4* Bp = (const float4*)(B + ((size_t)e * NGP + g) * 24);
        float Bg[24];
#pragma unroll
        for (int t2 = 0; t2 < 6; t2++) {
            float4 v = Bp[t2];
            Bg[4 * t2 + 0] = v.x; Bg[4 * t2 + 1] = v.y;
            Bg[4 * t2 + 2] = v.z; Bg[4 * t2 + 3] = v.w;
        }
        float s0 = 0.f, s1 = 0.f, s2 = 0.f;
#pragma unroll
        for (int j = 0; j < 8; j++) {
            s0 = fmaf(Bg[j],      ue[j], s0);
            s1 = fmaf(Bg[8 + j],  ue[j], s1);
            s2 = fmaf(Bg[16 + j], ue[j], s2);
        }
        const float ev  = s0 + s1;
        const float ev3 = ev * (1.0f / 3.0f);
        const float d00 = s0 - ev3, d11 = s1 - ev3, d22 = -ev3, d01 = 0.5f * s2;
        const float det = sqrtf(d00 * d00 + d11 * d11 + d22 * d22 + 2.0f * d01 * d01);
        const float rd  = __builtin_amdgcn_rcpf(det);
        const float es  = det * SQ23;
        d00s[g] = d00; d11s[g] = d11; d01s[g] = d01; rds[g] = rd;
        xps[g] = pk(fmaf(ev, si0, li0), fmaf(es, si1, li1));
    }

    // ---- layer 1: 2 -> 64, tanh, packed f16 output ----
    half2v h1[4][32];
#pragma unroll
    for (int m = 0; m < 32; m++) {
        const uint2 wp = ((const uint2*)sW1p)[m];
        const half2v wj0 = __builtin_bit_cast(half2v, wp.x);
        const half2v wj1 = __builtin_bit_cast(half2v, wp.y);
        const float2 bp = ((const float2*)sb1)[m];
#pragma unroll
        for (int g = 0; g < NGP; g++) {
            const float t0 = fast_tanh(fdot2(xps[g], wj0, bp.x));
            const float t1 = fast_tanh(fdot2(xps[g], wj1, bp.y));
            h1[g][m] = pk(t0, t1);
        }
    }

    // ---- layer 2 (64x64, tanh) fused with layer 3 (64->2) ----
    float g0s[4] = {b30, b30, b30, b30};
    float g1s[4] = {b31, b31, b31, b31};
    const uint4* wbase = (const uint4*)sW2p;
#pragma unroll 1
    for (int jg = 0; jg < 16; jg++) {
        const float4 bb = ((const float4*)sb2)[jg];
        float4 acc[4];
#pragma unroll
        for (int g = 0; g < NGP; g++) acc[g] = bb;
#pragma unroll
        for (int kp = 0; kp < 32; kp++) {
            const uint4 w = wbase[jg * 32 + kp];
            const half2v w0 = __builtin_bit_cast(half2v, w.x);
            const half2v w1 = __builtin_bit_cast(half2v, w.y);
            const half2v w2 = __builtin_bit_cast(half2v, w.z);
            const half2v w3v = __builtin_bit_cast(half2v, w.w);
#pragma unroll
            for (int g = 0; g < NGP; g++) {
                const half2v h = h1[g][kp];
                acc[g].x = fdot2(h, w0,  acc[g].x);
                acc[g].y = fdot2(h, w1,  acc[g].y);
                acc[g].z = fdot2(h, w2,  acc[g].z);
                acc[g].w = fdot2(h, w3v, acc[g].w);
            }
        }
        const float4 w3a = ((const float4*)sW3)[2 * jg];
        const float4 w3b = ((const float4*)sW3)[2 * jg + 1];
#pragma unroll
        for (int g = 0; g < NGP; g++) {
            const float t0 = fast_tanh(acc[g].x), t1 = fast_tanh(acc[g].y);
            const float t2 = fast_tanh(acc[g].z), t3 = fast_tanh(acc[g].w);
            g0s[g] = fmaf(t0, w3a.x, fmaf(t1, w3a.z, fmaf(t2, w3b.x, fmaf(t3, w3b.z, g0s[g]))));
            g1s[g] = fmaf(t0, w3a.y, fmaf(t1, w3a.w, fmaf(t2, w3b.y, fmaf(t3, w3b.w, g1s[g]))));
        }
    }

    // ---- epilogue: stress -> E_P (B re-read; L3-resident) ----
    float EP[8] = {0.f, 0.f, 0.f, 0.f, 0.f, 0.f, 0.f, 0.f};
#pragma unroll
    for (int g = 0; g < NGP; g++) {
        const float p = (g0s[g] - lg0) * isg0;
        const float q = (g1s[g] - lg1) * isg1;
        const float crd = SQ23 * q * rds[g];
        const float f0 = fmaf(crd, d00s[g], p) * wgt[g];
        const float f1 = fmaf(crd, d11s[g], p) * wgt[g];
        const float f2 = (crd * d01s[g]) * wgt[g];
        const float4* Bp = (const float4*)(B + ((size_t)e * NGP + g) * 24);
        float4 v0 = Bp[0], v1 = Bp[1], v2 = Bp[2], v3 = Bp[3], v4 = Bp[4], v5 = Bp[5];
        EP[0] = fmaf(v0.x, f0, fmaf(v2.x, f1, fmaf(v4.x, f2, EP[0])));
        EP[1] = fmaf(v0.y, f0, fmaf(v2.y, f1, fmaf(v4.y, f2, EP[1])));
        EP[2] = fmaf(v0.z, f0, fmaf(v2.z, f1, fmaf(v4.z, f2, EP[2])));
        EP[3] = fmaf(v0.w, f0, fmaf(v2.w, f1, fmaf(v4.w, f2, EP[3])));
        EP[4] = fmaf(v1.x, f0, fmaf(v3.x, f1, fmaf(v5.x, f2, EP[4])));
        EP[5] = fmaf(v1.y, f0, fmaf(v3.y, f1, fmaf(v5.y, f2, EP[5])));
        EP[6] = fmaf(v1.z, f0, fmaf(v3.z, f1, fmaf(v5.z, f2, EP[6])));
        EP[7] = fmaf(v1.w, f0, fmaf(v3.w, f1, fmaf(v5.w, f2, EP[7])));
    }

#pragma unroll
    for (int j = 0; j < 8; j++) atomicAdd(&F[ed[j]], EP[j]);
}

extern "C" void kernel_launch(void* const* d_in, const int* in_sizes, int n_in,
                              void* d_out, int out_size, void* d_ws, size_t ws_size,
                              hipStream_t stream) {
    const float* u           = (const float*)d_in[0];
    const float* B           = (const float*)d_in[1];
    const float* Jacc        = (const float*)d_in[2];
    const float* gp_w        = (const float*)d_in[3];
    const int*   conn        = (const int*)  d_in[4];
    const float* weight1     = (const float*)d_in[5];
    const float* scales_inp  = (const float*)d_in[6];
    const float* limits_inp  = (const float*)d_in[7];
    const float* scales_grad = (const float*)d_in[8];
    const float* limits_grad = (const float*)d_in[9];
    const float* W1          = (const float*)d_in[10];
    const float* b1          = (const float*)d_in[11];
    const float* W2          = (const float*)d_in[12];
    const float* b2          = (const float*)d_in[13];
    const float* W3          = (const float*)d_in[14];
    const float* b3          = (const float*)d_in[15];
    float* F = (float*)d_out;

    (void)hipMemsetAsync(d_out, 0, sizeof(float) * NDOF, stream);

    const int grid = (NELEM + 255) / 256;
    fem_force_kernel<<<grid, 256, 0, stream>>>(
        u, B, Jacc, gp_w, conn, weight1, scales_inp, limits_inp,
        scales_grad, limits_grad, W1, b1, W2, b2, W3, b3, F);
}

// Round 4
// 525.147 us; speedup vs baseline: 1.7348x; 1.0064x over previous
//
#include <hip/hip_runtime.h>

#define NELEM 500000
#define NGP 4
#define NDOF 500000
#define HID 64

typedef _Float16 half2v __attribute__((ext_vector_type(2)));
typedef _Float16 half8v __attribute__((ext_vector_type(8)));
typedef float float4v __attribute__((ext_vector_type(4)));

__device__ __forceinline__ half2v pk(float a, float b) {
    return __builtin_bit_cast(half2v, __builtin_amdgcn_cvt_pkrtz(a, b));
}
__device__ __forceinline__ float fast_tanh(float x) {
    float cx = __builtin_amdgcn_fmed3f(x, -15.0f, 15.0f);
    float e = __expf(2.0f * cx);
    float r = __builtin_amdgcn_rcpf(e + 1.0f);
    return fmaf(-2.0f, r, 1.0f);
}
__device__ __forceinline__ float fdot2(half2v a, half2v b, float c) {
    return __builtin_amdgcn_fdot2(a, b, c, false);
}

// 3-phase: per-thread strain -> wave-level MFMA MLP (W2 resident in B-frag
// VGPRs, LDS only for the 4B/GP activations) -> per-thread stress+scatter.
__global__ __launch_bounds__(256, 2) void fem_force_kernel(
    const float* __restrict__ u, const float* __restrict__ B,
    const float* __restrict__ Jacc, const float* __restrict__ gp_w,
    const int* __restrict__ conn, const float* __restrict__ weight1,
    const float* __restrict__ scales_inp, const float* __restrict__ limits_inp,
    const float* __restrict__ scales_grad, const float* __restrict__ limits_grad,
    const float* __restrict__ W1, const float* __restrict__ b1,
    const float* __restrict__ W2, const float* __restrict__ b2,
    const float* __restrict__ W3, const float* __restrict__ b3,
    float* __restrict__ F)
{
    __shared__ uint   sX[1024];      // packed-f16 (x0,x1) per GP-row
    __shared__ float2 sG[4][256];    // MLP outputs, [gp][element] planes

    const int tid  = threadIdx.x;
    const int lane = tid & 63;
    const int wv   = tid >> 6;
    const int quad = lane >> 4;
    const int l15  = lane & 15;
    const int e    = blockIdx.x * 256 + tid;
    const bool valid = (e < NELEM);

    const float SQ23 = 0.816496580927726f;
    const float si0 = scales_inp[0], si1 = scales_inp[1];
    const float li0 = limits_inp[0], li1 = limits_inp[1];
    const float isg0 = 1.0f / scales_grad[0], isg1 = 1.0f / scales_grad[1];
    const float lg0 = limits_grad[0], lg1 = limits_grad[1];
    const float b30 = b3[0], b31 = b3[1];

    // ---- per-lane weight fragments (loaded once, registers for the kernel) ----
    // Layer1: lane's 16 k's are f*32 + quad*8 + j  (A-layout cols)
    half2v w1p[16];
    float  b1v[16];
#pragma unroll
    for (int f = 0; f < 2; f++)
#pragma unroll
        for (int j = 0; j < 8; j++) {
            const int k = f * 32 + quad * 8 + j;
            w1p[f * 8 + j] = pk(W1[k], W1[HID + k]);
            b1v[f * 8 + j] = b1[k];
        }
    // Layer2 B-frags: B[k = f*32+quad*8+j][n = t*16+l15], f16 packed pairs
    half8v bf[4][2];
#pragma unroll
    for (int t = 0; t < 4; t++)
#pragma unroll
        for (int f = 0; f < 2; f++) {
            union { half8v v; uint uu[4]; } tmp;
#pragma unroll
            for (int jj = 0; jj < 4; jj++) {
                const int k0 = f * 32 + quad * 8 + 2 * jj;
                const int n  = t * 16 + l15;
                tmp.uu[jj] = __builtin_bit_cast(uint,
                    pk(W2[k0 * HID + n], W2[(k0 + 1) * HID + n]));
            }
            bf[t][f] = tmp.v;
        }
    // Layer2 bias + layer3 weights per output col n = t*16+l15
    float b2f[4], w3a[4], w3b[4];
#pragma unroll
    for (int t = 0; t < 4; t++) {
        const int n = t * 16 + l15;
        b2f[t] = b2[n];
        w3a[t] = W3[2 * n];
        w3b[t] = W3[2 * n + 1];
    }

    // ---- phase 1: strain invariants per element, activations to LDS ----
    float d00s[4], d11s[4], d01s[4], rds[4], wgt4[4];
    int ed[8];
    uint4 xq = make_uint4(0u, 0u, 0u, 0u);
    if (valid) {
        const int4 c4 = ((const int4*)conn)[e];
        ed[0] = 2 * c4.x; ed[1] = ed[0] + 1;
        ed[2] = 2 * c4.y; ed[3] = ed[2] + 1;
        ed[4] = 2 * c4.z; ed[5] = ed[4] + 1;
        ed[6] = 2 * c4.w; ed[7] = ed[6] + 1;
        float ue[8];
#pragma unroll
        for (int j = 0; j < 8; j++) ue[j] = weight1[ed[j]] * u[ed[j]];

        const float4 jv = ((const float4*)Jacc)[e];
        const float4 gw = ((const float4*)gp_w)[0];
        wgt4[0] = jv.x * gw.x; wgt4[1] = jv.y * gw.y;
        wgt4[2] = jv.z * gw.z; wgt4[3] = jv.w * gw.w;

        uint xs[4];
#pragma unroll
        for (int g = 0; g < NGP; g++) {
            const float4* Bp = (const float4*)(B + ((size_t)e * NGP + g) * 24);
            float Bg[24];
#pragma unroll
            for (int t2 = 0; t2 < 6; t2++) {
                float4 v = Bp[t2];
                Bg[4 * t2 + 0] = v.x; Bg[4 * t2 + 1] = v.y;
                Bg[4 * t2 + 2] = v.z; Bg[4 * t2 + 3] = v.w;
            }
            float s0 = 0.f, s1 = 0.f, s2 = 0.f;
#pragma unroll
            for (int j = 0; j < 8; j++) {
                s0 = fmaf(Bg[j],      ue[j], s0);
                s1 = fmaf(Bg[8 + j],  ue[j], s1);
                s2 = fmaf(Bg[16 + j], ue[j], s2);
            }
            const float ev  = s0 + s1;
            const float ev3 = ev * (1.0f / 3.0f);
            const float d00 = s0 - ev3, d11 = s1 - ev3, d22 = -ev3, d01 = 0.5f * s2;
            const float det = sqrtf(d00 * d00 + d11 * d11 + d22 * d22 + 2.0f * d01 * d01);
            const float rd  = __builtin_amdgcn_rcpf(det);
            const float es  = det * SQ23;
            d00s[g] = d00; d11s[g] = d11; d01s[g] = d01; rds[g] = rd;
            xs[g] = __builtin_bit_cast(uint, pk(fmaf(ev, si0, li0), fmaf(es, si1, li1)));
        }
        xq = make_uint4(xs[0], xs[1], xs[2], xs[3]);
    }
    ((uint4*)sX)[tid] = xq;   // invalid lanes write zeros
    __syncthreads();

    // ---- phase 2: wave-level MFMA MLP over this wave's 256 GP-rows ----
#pragma unroll 1
    for (int rt = 0; rt < 16; rt++) {
        const int tb = wv * 256 + rt * 16;
        const half2v xp = __builtin_bit_cast(half2v, sX[tb + l15]);

        // layer 1 -> A-frags (row m = l15, cols per lane)
        union { half8v v; uint uu[4]; } A0, A1;
#pragma unroll
        for (int jj = 0; jj < 4; jj++) {
            const float t0 = fast_tanh(fdot2(xp, w1p[2 * jj],     b1v[2 * jj]));
            const float t1 = fast_tanh(fdot2(xp, w1p[2 * jj + 1], b1v[2 * jj + 1]));
            const float t2 = fast_tanh(fdot2(xp, w1p[8 + 2 * jj],     b1v[8 + 2 * jj]));
            const float t3 = fast_tanh(fdot2(xp, w1p[8 + 2 * jj + 1], b1v[8 + 2 * jj + 1]));
            A0.uu[jj] = __builtin_bit_cast(uint, pk(t0, t1));
            A1.uu[jj] = __builtin_bit_cast(uint, pk(t2, t3));
        }

        // layer 2 via MFMA + tanh + layer-3 partials
        float s0[4] = {0.f, 0.f, 0.f, 0.f};
        float s1[4] = {0.f, 0.f, 0.f, 0.f};
#pragma unroll
        for (int t = 0; t < 4; t++) {
            float4v c = {b2f[t], b2f[t], b2f[t], b2f[t]};
            c = __builtin_amdgcn_mfma_f32_16x16x32_f16(A0.v, bf[t][0], c, 0, 0, 0);
            c = __builtin_amdgcn_mfma_f32_16x16x32_f16(A1.v, bf[t][1], c, 0, 0, 0);
#pragma unroll
            for (int reg = 0; reg < 4; reg++) {
                const float h = fast_tanh(c[reg]);
                s0[reg] = fmaf(h, w3a[t], s0[reg]);
                s1[reg] = fmaf(h, w3b[t], s1[reg]);
            }
        }
        // reduce over the 16 col-lanes (xor masks < 16 stay in the group)
#pragma unroll
        for (int mask = 1; mask < 16; mask <<= 1) {
#pragma unroll
            for (int reg = 0; reg < 4; reg++) {
                s0[reg] += __shfl_xor(s0[reg], mask, 64);
                s1[reg] += __shfl_xor(s1[reg], mask, 64);
            }
        }
        // writer lanes l15<4 emit row (quad*4 + l15) of this tile
        if (l15 < 4) {
            float a = s0[0], b = s1[0];
            if (l15 == 1) { a = s0[1]; b = s1[1]; }
            if (l15 == 2) { a = s0[2]; b = s1[2]; }
            if (l15 == 3) { a = s0[3]; b = s1[3]; }
            const int gi = tb + quad * 4 + l15;
            sG[gi & 3][gi >> 2] = make_float2(a, b);
        }
    }
    __syncthreads();

    // ---- phase 3: stress -> E_P -> scatter ----
    if (valid) {
        float EP[8] = {0.f, 0.f, 0.f, 0.f, 0.f, 0.f, 0.f, 0.f};
#pragma unroll
        for (int g = 0; g < NGP; g++) {
            const float2 gv = sG[g][tid];
            const float p = (gv.x + b30 - lg0) * isg0;
            const float q = (gv.y + b31 - lg1) * isg1;
            const float crd = SQ23 * q * rds[g];
            const float f0 = fmaf(crd, d00s[g], p) * wgt4[g];
            const float f1 = fmaf(crd, d11s[g], p) * wgt4[g];
            const float f2 = (crd * d01s[g]) * wgt4[g];
            const float4* Bp = (const float4*)(B + ((size_t)e * NGP + g) * 24);
            float4 v0 = Bp[0], v1 = Bp[1], v2 = Bp[2], v3 = Bp[3], v4 = Bp[4], v5 = Bp[5];
            EP[0] = fmaf(v0.x, f0, fmaf(v2.x, f1, fmaf(v4.x, f2, EP[0])));
            EP[1] = fmaf(v0.y, f0, fmaf(v2.y, f1, fmaf(v4.y, f2, EP[1])));
            EP[2] = fmaf(v0.z, f0, fmaf(v2.z, f1, fmaf(v4.z, f2, EP[2])));
            EP[3] = fmaf(v0.w, f0, fmaf(v2.w, f1, fmaf(v4.w, f2, EP[3])));
            EP[4] = fmaf(v1.x, f0, fmaf(v3.x, f1, fmaf(v5.x, f2, EP[4])));
            EP[5] = fmaf(v1.y, f0, fmaf(v3.y, f1, fmaf(v5.y, f2, EP[5])));
            EP[6] = fmaf(v1.z, f0, fmaf(v3.z, f1, fmaf(v5.z, f2, EP[6])));
            EP[7] = fmaf(v1.w, f0, fmaf(v3.w, f1, fmaf(v5.w, f2, EP[7])));
        }
#pragma unroll
        for (int j = 0; j < 8; j++) atomicAdd(&F[ed[j]], EP[j]);
    }
}

extern "C" void kernel_launch(void* const* d_in, const int* in_sizes, int n_in,
                              void* d_out, int out_size, void* d_ws, size_t ws_size,
                              hipStream_t stream) {
    const float* u           = (const float*)d_in[0];
    const float* B           = (const float*)d_in[1];
    const float* Jacc        = (const float*)d_in[2];
    const float* gp_w        = (const float*)d_in[3];
    const int*   conn        = (const int*)  d_in[4];
    const float* weight1     = (const float*)d_in[5];
    const float* scales_inp  = (const float*)d_in[6];
    const float* limits_inp  = (const float*)d_in[7];
    const float* scales_grad = (const float*)d_in[8];
    const float* limits_grad = (const float*)d_in[9];
    const float* W1          = (const float*)d_in[10];
    const float* b1          = (const float*)d_in[11];
    const float* W2          = (const float*)d_in[12];
    const float* b2          = (const float*)d_in[13];
    const float* W3          = (const float*)d_in[14];
    const float* b3          = (const float*)d_in[15];
    float* F = (float*)d_out;

    (void)hipMemsetAsync(d_out, 0, sizeof(float) * NDOF, stream);

    const int grid = (NELEM + 255) / 256;
    fem_force_kernel<<<grid, 256, 0, stream>>>(
        u, B, Jacc, gp_w, conn, weight1, scales_inp, limits_inp,
        scales_grad, limits_grad, W1, b1, W2, b2, W3, b3, F);
}